// Round 7
// baseline (538.271 us; speedup 1.0000x reference)
//
#include <hip/hip_runtime.h>
#include <hip/hip_bf16.h>

#define BT 4096        // B*T rows
#define TT 1024        // T
#define HN 16          // heads

typedef __attribute__((ext_vector_type(8))) short bf16x8;
typedef __attribute__((ext_vector_type(4))) float f32x4;

__device__ __forceinline__ unsigned short f2bf(float f) {
    unsigned u = __builtin_bit_cast(unsigned, f);
    unsigned r = (u + 0x7fffu + ((u >> 16) & 1u)) >> 16;
    return (unsigned short)r;
}

// pack 2 f32 -> bf16x2 (RNE) as u32
__device__ __forceinline__ unsigned pk2bf(float a, float b) {
    return (unsigned)f2bf(a) | ((unsigned)f2bf(b) << 16);
}

__device__ __forceinline__ void g2l16(const void* g, void* l) {
    __builtin_amdgcn_global_load_lds(
        (__attribute__((address_space(1))) void*)(g),
        (__attribute__((address_space(3))) void*)(l), 16, 0, 0);
}

// tanh-approx gelu via hardware exp; overflow-safe
__device__ __forceinline__ float gelu_f(float v) {
    float t = v * (0.7978845608f + 0.0356774081f * v * v);
    float e = __expf(2.f * t);
    float th = 1.f - 2.f / (e + 1.f);
    return 0.5f * v * (1.f + th);
}

// ---------------------------------------------------------------- fused weight transpose
struct TransJobs {
    const float* W[7];
    unsigned short* Wt[7];
    int K[7], N[7];
    int start[8];
};

__global__ __launch_bounds__(256)
void transpose_all(TransJobs J)
{
    __shared__ float tile[32][33];
    int bx = blockIdx.x;
    int j = 0;
#pragma unroll
    for (int t = 0; t < 7; ++t)
        if (bx >= J.start[t + 1]) j = t + 1;
    int t = bx - J.start[j];
    int K = J.K[j], N = J.N[j];
    int ntx = N >> 5;
    int n0 = (t % ntx) * 32, k0 = (t / ntx) * 32;
    const float* W = J.W[j];
    unsigned short* Wt = J.Wt[j];
    int tx = threadIdx.x, ty = threadIdx.y;
#pragma unroll
    for (int i = ty; i < 32; i += 8)
        tile[i][tx] = W[(size_t)(k0 + i) * N + n0 + tx];
    __syncthreads();
#pragma unroll
    for (int i = ty; i < 32; i += 8)
        Wt[(size_t)(n0 + i) * K + k0 + tx] = f2bf(tile[tx][i]);
}

// ---------------------------------------------------------------- V transpose (bf16)
__global__ __launch_bounds__(256)
void transpose_v(const unsigned short* __restrict__ v, unsigned short* __restrict__ vt,
                 int stride)
{
    __shared__ unsigned short tile[32][33];
    int d0 = blockIdx.x * 32, t0 = blockIdx.y * 32, bh = blockIdx.z;
    int b = bh >> 4, h = bh & 15;
    int tx = threadIdx.x, ty = threadIdx.y;
#pragma unroll
    for (int i = ty; i < 32; i += 8)
        tile[i][tx] = v[((size_t)b * TT + t0 + i) * stride + h * 64 + d0 + tx];
    __syncthreads();
#pragma unroll
    for (int i = ty; i < 32; i += 8)
        vt[((size_t)bh * 64 + d0 + i) * TT + t0 + tx] = tile[tx][i];
}

// ---------------------------------------------------------------- LN body (C=1024)
__device__ __forceinline__
void ln_row(const float* __restrict__ xr, const float* __restrict__ g,
            const float* __restrict__ bta, unsigned short* __restrict__ outr,
            float* red)
{
    float4 v = ((const float4*)xr)[threadIdx.x];
    float s = v.x + v.y + v.z + v.w;
    float q = v.x*v.x + v.y*v.y + v.z*v.z + v.w*v.w;
#pragma unroll
    for (int m = 1; m < 64; m <<= 1) {
        s += __shfl_xor(s, m, 64);
        q += __shfl_xor(q, m, 64);
    }
    int wave = threadIdx.x >> 6;
    if ((threadIdx.x & 63) == 0) { red[wave] = s; red[4 + wave] = q; }
    __syncthreads();
    s = red[0] + red[1] + red[2] + red[3];
    q = red[4] + red[5] + red[6] + red[7];
    float mean = s * (1.f / 1024.f);
    float var  = q * (1.f / 1024.f) - mean * mean;
    float rstd = rsqrtf(var + 1e-5f);
    float4 gv = ((const float4*)g)[threadIdx.x];
    float4 bv = ((const float4*)bta)[threadIdx.x];
    uint2 o;
    o.x = pk2bf((v.x - mean) * rstd * gv.x + bv.x, (v.y - mean) * rstd * gv.y + bv.y);
    o.y = pk2bf((v.z - mean) * rstd * gv.z + bv.z, (v.w - mean) * rstd * gv.w + bv.w);
    ((uint2*)outr)[threadIdx.x] = o;
}

__global__ __launch_bounds__(256)
void ln_kernel(const float* __restrict__ x, const float* __restrict__ g,
               const float* __restrict__ bta, unsigned short* __restrict__ out)
{
    __shared__ float red[8];
    int row = blockIdx.x;
    ln_row(x + (size_t)row * 1024, g, bta, out + (size_t)row * 1024, red);
}

// fused: blocks [0,BT) = LN of x; blocks [BT,2BT) = bf16 cast of ctx
__global__ __launch_bounds__(256)
void ln_cast(const float* __restrict__ x, const float* __restrict__ g,
             const float* __restrict__ bta, unsigned short* __restrict__ outx,
             const float* __restrict__ ctx, unsigned short* __restrict__ outc)
{
    __shared__ float red[8];
    int bid = blockIdx.x;
    if (bid < BT) {
        ln_row(x + (size_t)bid * 1024, g, bta, outx + (size_t)bid * 1024, red);
    } else {
        size_t i = (size_t)(bid - BT) * 256 + threadIdx.x;
        float4 v = ((const float4*)ctx)[i];
        uint2 o;
        o.x = pk2bf(v.x, v.y);
        o.y = pk2bf(v.z, v.w);
        ((uint2*)outc)[i] = o;
    }
}

// ---------------------------------------------------------------- GEMM core (128x128 tile)
// XOR-swizzled LDS. OPERAND-SWAPPED: weights (lB) are the MFMA A-operand, so
// D[row=n][col=m] and each lane owns 4 CONSECUTIVE n -> vectorized stores.
// MODE 0: out bf16   MODE 1: out bf16, gelu   MODE 2: out f32, + res
// MODE 3: out f32 partial (no bias)
template<int MODE>
__device__ __forceinline__
void gemm_core(unsigned short* lA, unsigned short* lB,
               const unsigned short* __restrict__ A,
               const unsigned short* __restrict__ Bt,
               const float* __restrict__ bias,
               const float* __restrict__ res,
               void* __restrict__ outp,
               int N, int K, int m0, int n0, int kbeg, int kend)
{
    const int tid = threadIdx.x;
    const int wave = tid >> 6, lane = tid & 63;
    const int quad = lane >> 4, l16 = lane & 15;
    const int sw = l16 & 7;
    const int wN = (wave >> 1) * 64;   // weight (n) subtile base
    const int wM = (wave & 1) * 64;    // activation (m) subtile base

    f32x4 acc[4][4];                   // [i: n-subtile][j: m-subtile]
#pragma unroll
    for (int i = 0; i < 4; ++i)
#pragma unroll
        for (int j = 0; j < 4; ++j)
#pragma unroll
            for (int r = 0; r < 4; ++r) acc[i][j][r] = 0.f;

    for (int k0 = kbeg; k0 < kend; k0 += 64) {
        __syncthreads();
#pragma unroll
        for (int it = 0; it < 4; ++it) {
            int chunk = it * 256 + tid;
            int row = chunk >> 3, slot = chunk & 7;
            int kc = slot ^ (row & 7);                 // swizzled source chunk
            g2l16(A  + (size_t)(m0 + row) * K + k0 + kc * 8, &lA[chunk * 8]);
            g2l16(Bt + (size_t)(n0 + row) * K + k0 + kc * 8, &lB[chunk * 8]);
        }
        __syncthreads();
#pragma unroll
        for (int kk = 0; kk < 64; kk += 32) {
            const int gc = (kk >> 3) + quad;           // global chunk 0..7
            const int sl = (gc ^ sw) * 8;              // swizzled slot (elems)
            bf16x8 af[4], bfr[4];
#pragma unroll
            for (int i = 0; i < 4; ++i)                // A-operand = weights
                af[i] = *(const bf16x8*)&lB[(wN + i * 16 + l16) * 64 + sl];
#pragma unroll
            for (int j = 0; j < 4; ++j)                // B-operand = activations
                bfr[j] = *(const bf16x8*)&lA[(wM + j * 16 + l16) * 64 + sl];
#pragma unroll
            for (int i = 0; i < 4; ++i)
#pragma unroll
                for (int j = 0; j < 4; ++j)
                    acc[i][j] = __builtin_amdgcn_mfma_f32_16x16x32_bf16(af[i], bfr[j], acc[i][j], 0, 0, 0);
        }
    }

    // epilogue: n = n0+wN+i*16+quad*4+r (contiguous over r), m = m0+wM+j*16+l16
#pragma unroll
    for (int i = 0; i < 4; ++i) {
        const int nb = n0 + wN + i * 16 + quad * 4;
        float4 bs;
        if (MODE != 3) bs = *(const float4*)&bias[nb];
#pragma unroll
        for (int j = 0; j < 4; ++j) {
            const int m = m0 + wM + j * 16 + l16;
            const size_t idx = (size_t)m * N + nb;
            float v0 = acc[i][j][0], v1 = acc[i][j][1];
            float v2 = acc[i][j][2], v3 = acc[i][j][3];
            if (MODE != 3) { v0 += bs.x; v1 += bs.y; v2 += bs.z; v3 += bs.w; }
            if (MODE == 1) { v0 = gelu_f(v0); v1 = gelu_f(v1); v2 = gelu_f(v2); v3 = gelu_f(v3); }
            if (MODE == 2) {
                float4 rr = *(const float4*)&res[idx];
                float4 o; o.x = v0 + rr.x; o.y = v1 + rr.y; o.z = v2 + rr.z; o.w = v3 + rr.w;
                *(float4*)((float*)outp + idx) = o;
            } else if (MODE == 3) {
                float4 o; o.x = v0; o.y = v1; o.z = v2; o.w = v3;
                *(float4*)((float*)outp + idx) = o;
            } else {
                uint2 u;
                u.x = pk2bf(v0, v1);
                u.y = pk2bf(v2, v3);
                *(uint2*)((unsigned short*)outp + idx) = u;
            }
        }
    }
}

template<int MODE>
__global__ __launch_bounds__(256)
void gemm_bt(const unsigned short* __restrict__ A,
             const unsigned short* __restrict__ Bt,
             const float* __restrict__ bias,
             const float* __restrict__ res,
             void* __restrict__ outp,
             int M, int N, int K)
{
    __shared__ unsigned short lA[128 * 64];
    __shared__ unsigned short lB[128 * 64];
    gemm_core<MODE>(lA, lB, A, Bt, bias, res, outp, N, K,
                    blockIdx.y * 128, blockIdx.x * 128, 0, K);
}

// fused q + kv GEMM
__global__ __launch_bounds__(256)
void gemm_dual(const unsigned short* __restrict__ A1, const unsigned short* __restrict__ B1,
               const float* __restrict__ b1, unsigned short* __restrict__ o1p, int N1, int nbx1,
               const unsigned short* __restrict__ A2, const unsigned short* __restrict__ B2,
               const float* __restrict__ b2, unsigned short* __restrict__ o2p, int N2,
               int K)
{
    __shared__ unsigned short lA[128 * 64];
    __shared__ unsigned short lB[128 * 64];
    int bx = blockIdx.x;
    if (bx < nbx1)
        gemm_core<0>(lA, lB, A1, B1, b1, nullptr, o1p, N1, K,
                     blockIdx.y * 128, bx * 128, 0, K);
    else
        gemm_core<0>(lA, lB, A2, B2, b2, nullptr, o2p, N2, K,
                     blockIdx.y * 128, (bx - nbx1) * 128, 0, K);
}

// split-K GEMM: grid.z = 2 slices of K/2, fp32 partials, no bias
__global__ __launch_bounds__(256)
void gemm_splitk(const unsigned short* __restrict__ A,
                 const unsigned short* __restrict__ Bt,
                 float* __restrict__ part,
                 int M, int N, int K, int kslice)
{
    __shared__ unsigned short lA[128 * 64];
    __shared__ unsigned short lB[128 * 64];
    int kz = blockIdx.z;
    gemm_core<3>(lA, lB, A, Bt, nullptr, nullptr,
                 part + (size_t)kz * M * N, N, K,
                 blockIdx.y * 128, blockIdx.x * 128,
                 kz * kslice, (kz + 1) * kslice);
}

// reduce 2 partials + bias + res -> f32 out
__global__ __launch_bounds__(256)
void reduce2(const float* __restrict__ part, const float* __restrict__ bias,
             const float* __restrict__ res, float* __restrict__ out, int MN)
{
    int i = blockIdx.x * 256 + threadIdx.x;
    const float4* p = (const float4*)part;
    int q = MN >> 2;
    float4 a = p[i], b = p[i + q];
    float4 bs = ((const float4*)bias)[i & 255];
    float4 rr = ((const float4*)res)[i];
    float4 o;
    o.x = a.x + b.x + bs.x + rr.x;
    o.y = a.y + b.y + bs.y + rr.y;
    o.z = a.z + b.z + bs.z + rr.z;
    o.w = a.w + b.w + bs.w + rr.w;
    ((float4*)out)[i] = o;
}

// ---------------------------------------------------------------- small GEMM (64x128 tile)
// operand-swapped like gemm_core; f32 out + bias + res
__global__ __launch_bounds__(256)
void gemm_small2(const unsigned short* __restrict__ A,
                 const unsigned short* __restrict__ Bt,
                 const float* __restrict__ bias,
                 const float* __restrict__ res,
                 float* __restrict__ outp,
                 int M, int N, int K)
{
    __shared__ unsigned short lA[64 * 64];
    __shared__ unsigned short lB[128 * 64];
    const int tid = threadIdx.x;
    const int wave = tid >> 6, lane = tid & 63;
    const int quad = lane >> 4, l16 = lane & 15;
    const int sw = l16 & 7;
    const int m0 = blockIdx.y * 64, n0 = blockIdx.x * 128;
    const int wM = (wave >> 1) * 32;   // m-side (lA, 64 rows)
    const int wN = (wave & 1) * 64;    // n-side (lB, 128 rows)

    f32x4 acc[4][2];                   // [i: n-subtile][j: m-subtile]
#pragma unroll
    for (int i = 0; i < 4; ++i)
#pragma unroll
        for (int j = 0; j < 2; ++j)
#pragma unroll
            for (int r = 0; r < 4; ++r) acc[i][j][r] = 0.f;

    for (int k0 = 0; k0 < K; k0 += 64) {
        __syncthreads();
#pragma unroll
        for (int it = 0; it < 6; ++it) {
            int chunk = it * 256 + tid;
            if (chunk < 512) {
                int row = chunk >> 3, slot = chunk & 7;
                int kc = slot ^ (row & 7);
                g2l16(A + (size_t)(m0 + row) * K + k0 + kc * 8, &lA[chunk * 8]);
            } else {
                int cb = chunk - 512;
                int row = cb >> 3, slot = cb & 7;
                int kc = slot ^ (row & 7);
                g2l16(Bt + (size_t)(n0 + row) * K + k0 + kc * 8, &lB[cb * 8]);
            }
        }
        __syncthreads();
#pragma unroll
        for (int kk = 0; kk < 64; kk += 32) {
            const int gc = (kk >> 3) + quad;
            const int sl = (gc ^ sw) * 8;
            bf16x8 af[4], bfr[2];
#pragma unroll
            for (int i = 0; i < 4; ++i)
                af[i] = *(const bf16x8*)&lB[(wN + i * 16 + l16) * 64 + sl];
#pragma unroll
            for (int j = 0; j < 2; ++j)
                bfr[j] = *(const bf16x8*)&lA[(wM + j * 16 + l16) * 64 + sl];
#pragma unroll
            for (int i = 0; i < 4; ++i)
#pragma unroll
                for (int j = 0; j < 2; ++j)
                    acc[i][j] = __builtin_amdgcn_mfma_f32_16x16x32_bf16(af[i], bfr[j], acc[i][j], 0, 0, 0);
        }
    }

#pragma unroll
    for (int i = 0; i < 4; ++i) {
        const int nb = n0 + wN + i * 16 + quad * 4;
        float4 bs = *(const float4*)&bias[nb];
#pragma unroll
        for (int j = 0; j < 2; ++j) {
            const int m = m0 + wM + j * 16 + l16;
            const size_t idx = (size_t)m * N + nb;
            float4 rr = *(const float4*)&res[idx];
            float4 o;
            o.x = acc[i][j][0] + bs.x + rr.x;
            o.y = acc[i][j][1] + bs.y + rr.y;
            o.z = acc[i][j][2] + bs.z + rr.z;
            o.w = acc[i][j][3] + bs.w + rr.w;
            *(float4*)&outp[idx] = o;
        }
    }
}

// ---------------------------------------------------------------- flash attention v2
__global__ __launch_bounds__(256)
void attn_kernel(const unsigned short* __restrict__ qp,
                 const unsigned short* __restrict__ kp,
                 const unsigned short* __restrict__ vt,
                 unsigned short* __restrict__ op,
                 int qstride, int kstride, int causal)
{
    __shared__ unsigned short lK[64 * 72];
    __shared__ unsigned short lV[64 * 72];
    __shared__ unsigned short lP[4][16 * 72];

    const int tid = threadIdx.x;
    const int wave = tid >> 6, lane = tid & 63;
    const int quad = lane >> 4, l16 = lane & 15;
    const int bh = blockIdx.y, b = bh >> 4, h = bh & 15;
    const int qtile = causal ? (gridDim.x - 1 - blockIdx.x) : blockIdx.x;
    const int q0 = qtile * 64;
    const size_t rowbase = (size_t)b * TT;
    const int hoff = h * 64;
    const unsigned short* vbase = vt + (size_t)bh * 64 * TT;

    bf16x8 qf[2];
    {
        int qrow = q0 + wave * 16 + l16;
        const unsigned short* qrp = qp + (rowbase + qrow) * (size_t)qstride + hoff;
        qf[0] = *(const bf16x8*)(qrp + quad * 8);
        qf[1] = *(const bf16x8*)(qrp + 32 + quad * 8);
    }

    f32x4 oacc[4];
#pragma unroll
    for (int jd = 0; jd < 4; ++jd)
#pragma unroll
        for (int r = 0; r < 4; ++r) oacc[jd][r] = 0.f;
    float mrun = -1e30f, lrun = 0.f;

    const int nkt = causal ? (qtile + 1) : (TT / 64);
    for (int kt = 0; kt < nkt; ++kt) {
        __syncthreads();
#pragma unroll
        for (int it = 0; it < 2; ++it) {
            int c = it * 256 + tid;
            int r8 = c >> 3, cc = c & 7;
            *(bf16x8*)&lK[r8 * 72 + cc * 8] =
                *(const bf16x8*)(kp + (rowbase + kt * 64 + r8) * (size_t)kstride + hoff + cc * 8);
            *(bf16x8*)&lV[r8 * 72 + cc * 8] =
                *(const bf16x8*)(vbase + (size_t)r8 * TT + kt * 64 + cc * 8);
        }
        __syncthreads();

        f32x4 s[4];
#pragma unroll
        for (int i = 0; i < 4; ++i)
#pragma unroll
            for (int r = 0; r < 4; ++r) s[i][r] = 0.f;
#pragma unroll
        for (int kk = 0; kk < 2; ++kk) {
            bf16x8 kf[4];
#pragma unroll
            for (int i = 0; i < 4; ++i)
                kf[i] = *(const bf16x8*)&lK[(i * 16 + l16) * 72 + kk * 32 + quad * 8];
#pragma unroll
            for (int i = 0; i < 4; ++i)
                s[i] = __builtin_amdgcn_mfma_f32_16x16x32_bf16(kf[i], qf[kk], s[i], 0, 0, 0);
        }

        const int qg = q0 + wave * 16 + l16;
        const bool domask = (causal != 0) && (kt == qtile);
        float mloc = -1e30f;
#pragma unroll
        for (int i = 0; i < 4; ++i)
#pragma unroll
            for (int r = 0; r < 4; ++r) {
                float v = s[i][r] * 0.125f;
                if (domask) {
                    int kg = kt * 64 + i * 16 + quad * 4 + r;
                    if (kg > qg) v = -1e30f;
                }
                s[i][r] = v;
                mloc = fmaxf(mloc, v);
            }
        mloc = fmaxf(mloc, __shfl_xor(mloc, 16, 64));
        mloc = fmaxf(mloc, __shfl_xor(mloc, 32, 64));
        float mn = fmaxf(mrun, mloc);
        float alpha = __expf(mrun - mn);
        mrun = mn;
        float ls = 0.f;
#pragma unroll
        for (int i = 0; i < 4; ++i)
#pragma unroll
            for (int r = 0; r < 4; ++r) {
                float p = __expf(s[i][r] - mn);
                s[i][r] = p;
                ls += p;
            }
        ls += __shfl_xor(ls, 16, 64);
        ls += __shfl_xor(ls, 32, 64);
        lrun = lrun * alpha + ls;

        float arow[4];
#pragma unroll
        for (int r = 0; r < 4; ++r)
            arow[r] = __shfl(alpha, quad * 4 + r, 64);
#pragma unroll
        for (int jd = 0; jd < 4; ++jd)
#pragma unroll
            for (int r = 0; r < 4; ++r) oacc[jd][r] *= arow[r];

        unsigned short* pw = lP[wave];
#pragma unroll
        for (int i = 0; i < 4; ++i) {
            ushort4 pk;
            pk.x = f2bf(s[i][0]); pk.y = f2bf(s[i][1]);
            pk.z = f2bf(s[i][2]); pk.w = f2bf(s[i][3]);
            *(ushort4*)&pw[l16 * 72 + i * 16 + quad * 4] = pk;
        }

#pragma unroll
        for (int kk = 0; kk < 2; ++kk) {
            bf16x8 pf = *(const bf16x8*)&pw[l16 * 72 + kk * 32 + quad * 8];
            bf16x8 vf[4];
#pragma unroll
            for (int jd = 0; jd < 4; ++jd)
                vf[jd] = *(const bf16x8*)&lV[(jd * 16 + l16) * 72 + kk * 32 + quad * 8];
#pragma unroll
            for (int jd = 0; jd < 4; ++jd)
                oacc[jd] = __builtin_amdgcn_mfma_f32_16x16x32_bf16(pf, vf[jd], oacc[jd], 0, 0, 0);
        }
    }

    float ir[4];
#pragma unroll
    for (int r = 0; r < 4; ++r)
        ir[r] = 1.f / __shfl(lrun, quad * 4 + r, 64);
#pragma unroll
    for (int r = 0; r < 4; ++r) {
        int qg = q0 + wave * 16 + quad * 4 + r;
        unsigned short* orow = op + (rowbase + qg) * (size_t)1024 + hoff;
#pragma unroll
        for (int jd = 0; jd < 4; ++jd)
            orow[jd * 16 + l16] = f2bf(oacc[jd][r] * ir[r]);
    }
}

// ---------------------------------------------------------------- launch
extern "C" void kernel_launch(void* const* d_in, const int* in_sizes, int n_in,
                              void* d_out, int out_size, void* d_ws, size_t ws_size,
                              hipStream_t stream)
{
    const float* x     = (const float*)d_in[0];
    const float* ctx   = (const float*)d_in[1];
    const float* ln1_g = (const float*)d_in[2];
    const float* ln1_b = (const float*)d_in[3];
    const float* qkv_w = (const float*)d_in[4];
    const float* qkv_b = (const float*)d_in[5];
    const float* aow   = (const float*)d_in[6];
    const float* aob   = (const float*)d_in[7];
    const float* lnc_g = (const float*)d_in[8];
    const float* lnc_b = (const float*)d_in[9];
    const float* q_w   = (const float*)d_in[10];
    const float* q_b   = (const float*)d_in[11];
    const float* kv_w  = (const float*)d_in[12];
    const float* kv_b  = (const float*)d_in[13];
    const float* cow   = (const float*)d_in[14];
    const float* cob   = (const float*)d_in[15];
    const float* ln2_g = (const float*)d_in[16];
    const float* ln2_b = (const float*)d_in[17];
    const float* f1w   = (const float*)d_in[18];
    const float* f1b   = (const float*)d_in[19];
    const float* f2w   = (const float*)d_in[20];
    const float* f2b   = (const float*)d_in[21];

    char* ws = (char*)d_ws;
    size_t off = 0;
    auto alloc = [&](size_t bytes) {
        char* p = ws + off;
        off += (bytes + 255) & ~(size_t)255;
        return p;
    };

    unsigned short* WtQKV = (unsigned short*)alloc((size_t)3072 * 1024 * 2);
    unsigned short* WtAO  = (unsigned short*)alloc((size_t)1024 * 1024 * 2);
    unsigned short* WtQ   = (unsigned short*)alloc((size_t)1024 * 1024 * 2);
    unsigned short* WtKV  = (unsigned short*)alloc((size_t)2048 * 1024 * 2);
    unsigned short* WtCO  = (unsigned short*)alloc((size_t)1024 * 1024 * 2);
    unsigned short* WtF1  = (unsigned short*)alloc((size_t)4096 * 1024 * 2);
    unsigned short* WtF2  = (unsigned short*)alloc((size_t)1024 * 4096 * 2);
    unsigned short* hA    = (unsigned short*)alloc((size_t)BT * 1024 * 2);
    unsigned short* ctxb  = (unsigned short*)alloc((size_t)BT * 1024 * 2);
    unsigned short* qkvb  = (unsigned short*)alloc((size_t)BT * 3072 * 2);
    unsigned short* o1    = (unsigned short*)alloc((size_t)BT * 1024 * 2);
    float*          x1    = (float*)alloc((size_t)BT * 1024 * 4);
    unsigned short* qb    = (unsigned short*)alloc((size_t)BT * 1024 * 2);
    unsigned short* kvb   = (unsigned short*)alloc((size_t)BT * 2048 * 2);
    unsigned short* o2    = (unsigned short*)alloc((size_t)BT * 1024 * 2);
    float*          x2    = (float*)alloc((size_t)BT * 1024 * 4);
    unsigned short* mid   = (unsigned short*)alloc((size_t)BT * 4096 * 2);
    unsigned short* vT1   = (unsigned short*)alloc((size_t)BT * 1024 * 2);
    unsigned short* vT2   = (unsigned short*)alloc((size_t)BT * 1024 * 2);

    float* partials = (float*)qkvb;   // dead by FFN2 time; 33.5 MB fits easily

    TransJobs J;
    J.W[0]=qkv_w; J.Wt[0]=WtQKV; J.K[0]=1024; J.N[0]=3072;
    J.W[1]=aow;   J.Wt[1]=WtAO;  J.K[1]=1024; J.N[1]=1024;
    J.W[2]=q_w;   J.Wt[2]=WtQ;   J.K[2]=1024; J.N[2]=1024;
    J.W[3]=kv_w;  J.Wt[3]=WtKV;  J.K[3]=1024; J.N[3]=2048;
    J.W[4]=cow;   J.Wt[4]=WtCO;  J.K[4]=1024; J.N[4]=1024;
    J.W[5]=f1w;   J.Wt[5]=WtF1;  J.K[5]=1024; J.N[5]=4096;
    J.W[6]=f2w;   J.Wt[6]=WtF2;  J.K[6]=4096; J.N[6]=1024;
    int acc = 0;
    for (int j = 0; j < 7; ++j) {
        J.start[j] = acc;
        acc += (J.N[j] / 32) * (J.K[j] / 32);
    }
    J.start[7] = acc;

    dim3 tb(32, 8);
    transpose_all<<<acc, tb, 0, stream>>>(J);

    // self-attention block (ln of x fused with ctx cast)
    ln_cast<<<2 * BT, 256, 0, stream>>>(x, ln1_g, ln1_b, hA, ctx, ctxb);
    gemm_bt<0><<<dim3(3072/128, BT/128), 256, 0, stream>>>(hA, WtQKV, qkv_b, nullptr, qkvb, BT, 3072, 1024);
    transpose_v<<<dim3(2, TT/32, 64), tb, 0, stream>>>(qkvb + 2048, vT1, 3072);
    attn_kernel<<<dim3(TT/64, 64), 256, 0, stream>>>(qkvb, qkvb + 1024, vT1, o1, 3072, 3072, 1);
    gemm_small2<<<dim3(1024/128, BT/64), 256, 0, stream>>>(o1, WtAO, aob, x, x1, BT, 1024, 1024);

    // cross-attention block
    ln_kernel<<<BT, 256, 0, stream>>>(x1, lnc_g, lnc_b, hA);
    gemm_dual<<<dim3(1024/128 + 2048/128, BT/128), 256, 0, stream>>>(
        hA, WtQ, q_b, qb, 1024, 1024/128,
        ctxb, WtKV, kv_b, kvb, 2048, 1024);
    transpose_v<<<dim3(2, TT/32, 64), tb, 0, stream>>>(kvb + 1024, vT2, 2048);
    attn_kernel<<<dim3(TT/64, 64), 256, 0, stream>>>(qb, kvb, vT2, o2, 1024, 2048, 0);
    gemm_small2<<<dim3(1024/128, BT/64), 256, 0, stream>>>(o2, WtCO, cob, x1, x2, BT, 1024, 1024);

    // FFN block
    ln_kernel<<<BT, 256, 0, stream>>>(x2, ln2_g, ln2_b, hA);
    gemm_bt<1><<<dim3(4096/128, BT/128), 256, 0, stream>>>(hA, WtF1, f1b, nullptr, mid, BT, 4096, 1024);
    gemm_splitk<<<dim3(1024/128, BT/128, 2), 256, 0, stream>>>(mid, WtF2, partials, BT, 1024, 4096, 2048);
    reduce2<<<BT * 1024 / 4 / 256, 256, 0, stream>>>(partials, f2b, x2, (float*)d_out, BT * 1024);
}

// Round 8
// 533.156 us; speedup vs baseline: 1.0096x; 1.0096x over previous
//
#include <hip/hip_runtime.h>
#include <hip/hip_bf16.h>

#define BT 4096        // B*T rows
#define TT 1024        // T
#define HN 16          // heads

typedef __attribute__((ext_vector_type(8))) short bf16x8;
typedef __attribute__((ext_vector_type(4))) float f32x4;
typedef __attribute__((ext_vector_type(16))) float f32x16;

__device__ __forceinline__ unsigned short f2bf(float f) {
    unsigned u = __builtin_bit_cast(unsigned, f);
    unsigned r = (u + 0x7fffu + ((u >> 16) & 1u)) >> 16;
    return (unsigned short)r;
}

// pack 2 f32 -> bf16x2 (RNE) as u32
__device__ __forceinline__ unsigned pk2bf(float a, float b) {
    return (unsigned)f2bf(a) | ((unsigned)f2bf(b) << 16);
}

__device__ __forceinline__ void g2l16(const void* g, void* l) {
    __builtin_amdgcn_global_load_lds(
        (__attribute__((address_space(1))) void*)(g),
        (__attribute__((address_space(3))) void*)(l), 16, 0, 0);
}

// tanh-approx gelu via hardware exp; overflow-safe
__device__ __forceinline__ float gelu_f(float v) {
    float t = v * (0.7978845608f + 0.0356774081f * v * v);
    float e = __expf(2.f * t);
    float th = 1.f - 2.f / (e + 1.f);
    return 0.5f * v * (1.f + th);
}

// ---------------------------------------------------------------- prep kernel
// blocks [0, nT): weight transpose 32x32 tiles (7 jobs)
// blocks [nT, nT+BT): LN of x -> bf16
// blocks [nT+BT, nT+2BT): bf16 cast of ctx
struct TransJobs {
    const float* W[7];
    unsigned short* Wt[7];
    int K[7], N[7];
    int start[8];
};

__device__ __forceinline__
void ln_row(const float* __restrict__ xr, const float* __restrict__ g,
            const float* __restrict__ bta, unsigned short* __restrict__ outr,
            float* red)
{
    float4 v = ((const float4*)xr)[threadIdx.x];
    float s = v.x + v.y + v.z + v.w;
    float q = v.x*v.x + v.y*v.y + v.z*v.z + v.w*v.w;
#pragma unroll
    for (int m = 1; m < 64; m <<= 1) {
        s += __shfl_xor(s, m, 64);
        q += __shfl_xor(q, m, 64);
    }
    int wave = threadIdx.x >> 6;
    if ((threadIdx.x & 63) == 0) { red[wave] = s; red[4 + wave] = q; }
    __syncthreads();
    s = red[0] + red[1] + red[2] + red[3];
    q = red[4] + red[5] + red[6] + red[7];
    float mean = s * (1.f / 1024.f);
    float var  = q * (1.f / 1024.f) - mean * mean;
    float rstd = rsqrtf(var + 1e-5f);
    float4 gv = ((const float4*)g)[threadIdx.x];
    float4 bv = ((const float4*)bta)[threadIdx.x];
    uint2 o;
    o.x = pk2bf((v.x - mean) * rstd * gv.x + bv.x, (v.y - mean) * rstd * gv.y + bv.y);
    o.y = pk2bf((v.z - mean) * rstd * gv.z + bv.z, (v.w - mean) * rstd * gv.w + bv.w);
    ((uint2*)outr)[threadIdx.x] = o;
}

__global__ __launch_bounds__(256)
void prep_kernel(TransJobs J, const float* __restrict__ x,
                 const float* __restrict__ g, const float* __restrict__ bta,
                 unsigned short* __restrict__ outx,
                 const float* __restrict__ ctx, unsigned short* __restrict__ outc)
{
    __shared__ float tile[32][33];
    __shared__ float red[8];
    int bid = blockIdx.x;
    const int nT = J.start[7];
    if (bid < nT) {
        int j = 0;
#pragma unroll
        for (int t = 0; t < 7; ++t)
            if (bid >= J.start[t + 1]) j = t + 1;
        int t = bid - J.start[j];
        int K = J.K[j], N = J.N[j];
        int ntx = N >> 5;
        int n0 = (t % ntx) * 32, k0 = (t / ntx) * 32;
        const float* W = J.W[j];
        unsigned short* Wt = J.Wt[j];
        int tx = threadIdx.x & 31, ty = threadIdx.x >> 5;
#pragma unroll
        for (int i = ty; i < 32; i += 8)
            tile[i][tx] = W[(size_t)(k0 + i) * N + n0 + tx];
        __syncthreads();
#pragma unroll
        for (int i = ty; i < 32; i += 8)
            Wt[(size_t)(n0 + i) * K + k0 + tx] = f2bf(tile[tx][i]);
    } else if (bid < nT + BT) {
        int row = bid - nT;
        ln_row(x + (size_t)row * 1024, g, bta, outx + (size_t)row * 1024, red);
    } else {
        size_t i = (size_t)(bid - nT - BT) * 256 + threadIdx.x;
        float4 v = ((const float4*)ctx)[i];
        uint2 o;
        o.x = pk2bf(v.x, v.y);
        o.y = pk2bf(v.z, v.w);
        ((uint2*)outc)[i] = o;
    }
}

__global__ __launch_bounds__(256)
void ln_kernel(const float* __restrict__ x, const float* __restrict__ g,
               const float* __restrict__ bta, unsigned short* __restrict__ out)
{
    __shared__ float red[8];
    int row = blockIdx.x;
    ln_row(x + (size_t)row * 1024, g, bta, out + (size_t)row * 1024, red);
}

// ---------------------------------------------------------------- V transpose (bf16)
__global__ __launch_bounds__(256)
void transpose_v(const unsigned short* __restrict__ v, unsigned short* __restrict__ vt,
                 int stride)
{
    __shared__ unsigned short tile[32][33];
    int d0 = blockIdx.x * 32, t0 = blockIdx.y * 32, bh = blockIdx.z;
    int b = bh >> 4, h = bh & 15;
    int tx = threadIdx.x, ty = threadIdx.y;
#pragma unroll
    for (int i = ty; i < 32; i += 8)
        tile[i][tx] = v[((size_t)b * TT + t0 + i) * stride + h * 64 + d0 + tx];
    __syncthreads();
#pragma unroll
    for (int i = ty; i < 32; i += 8)
        vt[((size_t)bh * 64 + d0 + i) * TT + t0 + tx] = tile[tx][i];
}

// ---------------------------------------------------------------- GEMM core (128x128 tile)
// 32x32x16 MFMA (2495 TF ceiling vs 2075 for 16x16 — m119), XOR-swizzled LDS,
// operand-swapped (weights = A-operand) so each lane owns 4 consecutive n.
// C/D: col=lane&31, row=(reg&3)+8*(reg>>2)+4*(lane>>5)  [m74/m101 verified]
// MODE 0: out bf16   MODE 1: out bf16, gelu   MODE 2: out f32, + res
// MODE 3: out f32 partial (no bias)
template<int MODE>
__device__ __forceinline__
void gemm_core(unsigned short* lA, unsigned short* lB,
               const unsigned short* __restrict__ A,
               const unsigned short* __restrict__ Bt,
               const float* __restrict__ bias,
               const float* __restrict__ res,
               void* __restrict__ outp,
               int N, int K, int m0, int n0, int kbeg, int kend)
{
    const int tid = threadIdx.x;
    const int wave = tid >> 6, lane = tid & 63;
    const int l32 = lane & 31, half = lane >> 5;
    const int sw = l32 & 7;
    const int wN = (wave >> 1) * 64;   // weight (n) subtile base
    const int wM = (wave & 1) * 64;    // activation (m) subtile base

    f32x16 acc[2][2];                  // [ti: n-subtile][tj: m-subtile]
#pragma unroll
    for (int i = 0; i < 2; ++i)
#pragma unroll
        for (int j = 0; j < 2; ++j)
#pragma unroll
            for (int r = 0; r < 16; ++r) acc[i][j][r] = 0.f;

    for (int k0 = kbeg; k0 < kend; k0 += 64) {
        __syncthreads();
#pragma unroll
        for (int it = 0; it < 4; ++it) {
            int chunk = it * 256 + tid;
            int row = chunk >> 3, slot = chunk & 7;
            int kc = slot ^ (row & 7);                 // swizzled source chunk
            g2l16(A  + (size_t)(m0 + row) * K + k0 + kc * 8, &lA[chunk * 8]);
            g2l16(Bt + (size_t)(n0 + row) * K + k0 + kc * 8, &lB[chunk * 8]);
        }
        __syncthreads();
#pragma unroll
        for (int ks = 0; ks < 4; ++ks) {               // K-step of 16
            const int gc = ks * 2 + half;              // global chunk 0..7
            const int sl = (gc ^ sw) * 8;              // swizzled slot (elems)
            bf16x8 af[2], bfr[2];
#pragma unroll
            for (int i = 0; i < 2; ++i)                // A-operand = weights
                af[i] = *(const bf16x8*)&lB[(wN + i * 32 + l32) * 64 + sl];
#pragma unroll
            for (int j = 0; j < 2; ++j)                // B-operand = activations
                bfr[j] = *(const bf16x8*)&lA[(wM + j * 32 + l32) * 64 + sl];
#pragma unroll
            for (int i = 0; i < 2; ++i)
#pragma unroll
                for (int j = 0; j < 2; ++j)
                    acc[i][j] = __builtin_amdgcn_mfma_f32_32x32x16_bf16(af[i], bfr[j], acc[i][j], 0, 0, 0);
        }
    }

    // epilogue: n = n0+wN+ti*32+g*8+half*4+r (r contiguous), m = m0+wM+tj*32+l32
#pragma unroll
    for (int i = 0; i < 2; ++i) {
#pragma unroll
        for (int g = 0; g < 4; ++g) {
            const int nb = n0 + wN + i * 32 + g * 8 + half * 4;
            float4 bs;
            if (MODE != 3) bs = *(const float4*)&bias[nb];
#pragma unroll
            for (int j = 0; j < 2; ++j) {
                const int m = m0 + wM + j * 32 + l32;
                const size_t idx = (size_t)m * N + nb;
                float v0 = acc[i][j][g * 4 + 0], v1 = acc[i][j][g * 4 + 1];
                float v2 = acc[i][j][g * 4 + 2], v3 = acc[i][j][g * 4 + 3];
                if (MODE != 3) { v0 += bs.x; v1 += bs.y; v2 += bs.z; v3 += bs.w; }
                if (MODE == 1) { v0 = gelu_f(v0); v1 = gelu_f(v1); v2 = gelu_f(v2); v3 = gelu_f(v3); }
                if (MODE == 2) {
                    float4 rr = *(const float4*)&res[idx];
                    float4 o; o.x = v0 + rr.x; o.y = v1 + rr.y; o.z = v2 + rr.z; o.w = v3 + rr.w;
                    *(float4*)((float*)outp + idx) = o;
                } else if (MODE == 3) {
                    float4 o; o.x = v0; o.y = v1; o.z = v2; o.w = v3;
                    *(float4*)((float*)outp + idx) = o;
                } else {
                    uint2 u;
                    u.x = pk2bf(v0, v1);
                    u.y = pk2bf(v2, v3);
                    *(uint2*)((unsigned short*)outp + idx) = u;
                }
            }
        }
    }
}

template<int MODE>
__global__ __launch_bounds__(256)
void gemm_bt(const unsigned short* __restrict__ A,
             const unsigned short* __restrict__ Bt,
             const float* __restrict__ bias,
             const float* __restrict__ res,
             void* __restrict__ outp,
             int M, int N, int K)
{
    __shared__ unsigned short lA[128 * 64];
    __shared__ unsigned short lB[128 * 64];
    gemm_core<MODE>(lA, lB, A, Bt, bias, res, outp, N, K,
                    blockIdx.y * 128, blockIdx.x * 128, 0, K);
}

// fused q + kv GEMM
__global__ __launch_bounds__(256)
void gemm_dual(const unsigned short* __restrict__ A1, const unsigned short* __restrict__ B1,
               const float* __restrict__ b1, unsigned short* __restrict__ o1p, int N1, int nbx1,
               const unsigned short* __restrict__ A2, const unsigned short* __restrict__ B2,
               const float* __restrict__ b2, unsigned short* __restrict__ o2p, int N2,
               int K)
{
    __shared__ unsigned short lA[128 * 64];
    __shared__ unsigned short lB[128 * 64];
    int bx = blockIdx.x;
    if (bx < nbx1)
        gemm_core<0>(lA, lB, A1, B1, b1, nullptr, o1p, N1, K,
                     blockIdx.y * 128, bx * 128, 0, K);
    else
        gemm_core<0>(lA, lB, A2, B2, b2, nullptr, o2p, N2, K,
                     blockIdx.y * 128, (bx - nbx1) * 128, 0, K);
}

// split-K GEMM: grid.z = 2 slices of K/2, fp32 partials, no bias
__global__ __launch_bounds__(256)
void gemm_splitk(const unsigned short* __restrict__ A,
                 const unsigned short* __restrict__ Bt,
                 float* __restrict__ part,
                 int M, int N, int K, int kslice)
{
    __shared__ unsigned short lA[128 * 64];
    __shared__ unsigned short lB[128 * 64];
    int kz = blockIdx.z;
    gemm_core<3>(lA, lB, A, Bt, nullptr, nullptr,
                 part + (size_t)kz * M * N, N, K,
                 blockIdx.y * 128, blockIdx.x * 128,
                 kz * kslice, (kz + 1) * kslice);
}

// reduce 2 partials + bias + res -> f32 out
__global__ __launch_bounds__(256)
void reduce2(const float* __restrict__ part, const float* __restrict__ bias,
             const float* __restrict__ res, float* __restrict__ out, int MN)
{
    int i = blockIdx.x * 256 + threadIdx.x;
    const float4* p = (const float4*)part;
    int q = MN >> 2;
    float4 a = p[i], b = p[i + q];
    float4 bs = ((const float4*)bias)[i & 255];
    float4 rr = ((const float4*)res)[i];
    float4 o;
    o.x = a.x + b.x + bs.x + rr.x;
    o.y = a.y + b.y + bs.y + rr.y;
    o.z = a.z + b.z + bs.z + rr.z;
    o.w = a.w + b.w + bs.w + rr.w;
    ((float4*)out)[i] = o;
}

// ---------------------------------------------------------------- small GEMM (64x128 tile)
// 32x32x16, operand-swapped; f32 out + bias + res
__global__ __launch_bounds__(256)
void gemm_small2(const unsigned short* __restrict__ A,
                 const unsigned short* __restrict__ Bt,
                 const float* __restrict__ bias,
                 const float* __restrict__ res,
                 float* __restrict__ outp,
                 int M, int N, int K)
{
    __shared__ unsigned short lA[64 * 64];
    __shared__ unsigned short lB[128 * 64];
    const int tid = threadIdx.x;
    const int wave = tid >> 6, lane = tid & 63;
    const int l32 = lane & 31, half = lane >> 5;
    const int sw = l32 & 7;
    const int m0 = blockIdx.y * 64, n0 = blockIdx.x * 128;
    const int wM = (wave >> 1) * 32;   // m-side (lA, 64 rows): 1 tile of 32
    const int wN = (wave & 1) * 64;    // n-side (lB, 128 rows): 2 tiles of 32

    f32x16 acc[2];                     // [ti: n-subtile]
#pragma unroll
    for (int i = 0; i < 2; ++i)
#pragma unroll
        for (int r = 0; r < 16; ++r) acc[i][r] = 0.f;

    for (int k0 = 0; k0 < K; k0 += 64) {
        __syncthreads();
#pragma unroll
        for (int it = 0; it < 6; ++it) {
            int chunk = it * 256 + tid;
            if (chunk < 512) {
                int row = chunk >> 3, slot = chunk & 7;
                int kc = slot ^ (row & 7);
                g2l16(A + (size_t)(m0 + row) * K + k0 + kc * 8, &lA[chunk * 8]);
            } else {
                int cb = chunk - 512;
                int row = cb >> 3, slot = cb & 7;
                int kc = slot ^ (row & 7);
                g2l16(Bt + (size_t)(n0 + row) * K + k0 + kc * 8, &lB[cb * 8]);
            }
        }
        __syncthreads();
#pragma unroll
        for (int ks = 0; ks < 4; ++ks) {
            const int gc = ks * 2 + half;
            const int sl = (gc ^ sw) * 8;
            bf16x8 bfr = *(const bf16x8*)&lA[(wM + l32) * 64 + sl];
            bf16x8 af[2];
#pragma unroll
            for (int i = 0; i < 2; ++i)
                af[i] = *(const bf16x8*)&lB[(wN + i * 32 + l32) * 64 + sl];
#pragma unroll
            for (int i = 0; i < 2; ++i)
                acc[i] = __builtin_amdgcn_mfma_f32_32x32x16_bf16(af[i], bfr, acc[i], 0, 0, 0);
        }
    }

#pragma unroll
    for (int i = 0; i < 2; ++i) {
#pragma unroll
        for (int g = 0; g < 4; ++g) {
            const int nb = n0 + wN + i * 32 + g * 8 + half * 4;
            float4 bs = *(const float4*)&bias[nb];
            const int m = m0 + wM + l32;
            const size_t idx = (size_t)m * N + nb;
            float4 rr = *(const float4*)&res[idx];
            float4 o;
            o.x = acc[i][g * 4 + 0] + bs.x + rr.x;
            o.y = acc[i][g * 4 + 1] + bs.y + rr.y;
            o.z = acc[i][g * 4 + 2] + bs.z + rr.z;
            o.w = acc[i][g * 4 + 3] + bs.w + rr.w;
            *(float4*)&outp[idx] = o;
        }
    }
}

// ---------------------------------------------------------------- flash attention v2
__global__ __launch_bounds__(256)
void attn_kernel(const unsigned short* __restrict__ qp,
                 const unsigned short* __restrict__ kp,
                 const unsigned short* __restrict__ vt,
                 unsigned short* __restrict__ op,
                 int qstride, int kstride, int causal)
{
    __shared__ unsigned short lK[64 * 72];
    __shared__ unsigned short lV[64 * 72];
    __shared__ unsigned short lP[4][16 * 72];

    const int tid = threadIdx.x;
    const int wave = tid >> 6, lane = tid & 63;
    const int quad = lane >> 4, l16 = lane & 15;
    const int bh = blockIdx.y, b = bh >> 4, h = bh & 15;
    const int qtile = causal ? (gridDim.x - 1 - blockIdx.x) : blockIdx.x;
    const int q0 = qtile * 64;
    const size_t rowbase = (size_t)b * TT;
    const int hoff = h * 64;
    const unsigned short* vbase = vt + (size_t)bh * 64 * TT;

    bf16x8 qf[2];
    {
        int qrow = q0 + wave * 16 + l16;
        const unsigned short* qrp = qp + (rowbase + qrow) * (size_t)qstride + hoff;
        qf[0] = *(const bf16x8*)(qrp + quad * 8);
        qf[1] = *(const bf16x8*)(qrp + 32 + quad * 8);
    }

    f32x4 oacc[4];
#pragma unroll
    for (int jd = 0; jd < 4; ++jd)
#pragma unroll
        for (int r = 0; r < 4; ++r) oacc[jd][r] = 0.f;
    float mrun = -1e30f, lrun = 0.f;

    const int nkt = causal ? (qtile + 1) : (TT / 64);
    for (int kt = 0; kt < nkt; ++kt) {
        __syncthreads();
#pragma unroll
        for (int it = 0; it < 2; ++it) {
            int c = it * 256 + tid;
            int r8 = c >> 3, cc = c & 7;
            *(bf16x8*)&lK[r8 * 72 + cc * 8] =
                *(const bf16x8*)(kp + (rowbase + kt * 64 + r8) * (size_t)kstride + hoff + cc * 8);
            *(bf16x8*)&lV[r8 * 72 + cc * 8] =
                *(const bf16x8*)(vbase + (size_t)r8 * TT + kt * 64 + cc * 8);
        }
        __syncthreads();

        f32x4 s[4];
#pragma unroll
        for (int i = 0; i < 4; ++i)
#pragma unroll
            for (int r = 0; r < 4; ++r) s[i][r] = 0.f;
#pragma unroll
        for (int kk = 0; kk < 2; ++kk) {
            bf16x8 kf[4];
#pragma unroll
            for (int i = 0; i < 4; ++i)
                kf[i] = *(const bf16x8*)&lK[(i * 16 + l16) * 72 + kk * 32 + quad * 8];
#pragma unroll
            for (int i = 0; i < 4; ++i)
                s[i] = __builtin_amdgcn_mfma_f32_16x16x32_bf16(kf[i], qf[kk], s[i], 0, 0, 0);
        }

        const int qg = q0 + wave * 16 + l16;
        const bool domask = (causal != 0) && (kt == qtile);
        float mloc = -1e30f;
#pragma unroll
        for (int i = 0; i < 4; ++i)
#pragma unroll
            for (int r = 0; r < 4; ++r) {
                float v = s[i][r] * 0.125f;
                if (domask) {
                    int kg = kt * 64 + i * 16 + quad * 4 + r;
                    if (kg > qg) v = -1e30f;
                }
                s[i][r] = v;
                mloc = fmaxf(mloc, v);
            }
        mloc = fmaxf(mloc, __shfl_xor(mloc, 16, 64));
        mloc = fmaxf(mloc, __shfl_xor(mloc, 32, 64));
        float mn = fmaxf(mrun, mloc);
        float alpha = __expf(mrun - mn);
        mrun = mn;
        float ls = 0.f;
#pragma unroll
        for (int i = 0; i < 4; ++i)
#pragma unroll
            for (int r = 0; r < 4; ++r) {
                float p = __expf(s[i][r] - mn);
                s[i][r] = p;
                ls += p;
            }
        ls += __shfl_xor(ls, 16, 64);
        ls += __shfl_xor(ls, 32, 64);
        lrun = lrun * alpha + ls;

        float arow[4];
#pragma unroll
        for (int r = 0; r < 4; ++r)
            arow[r] = __shfl(alpha, quad * 4 + r, 64);
#pragma unroll
        for (int jd = 0; jd < 4; ++jd)
#pragma unroll
            for (int r = 0; r < 4; ++r) oacc[jd][r] *= arow[r];

        unsigned short* pw = lP[wave];
#pragma unroll
        for (int i = 0; i < 4; ++i) {
            ushort4 pk;
            pk.x = f2bf(s[i][0]); pk.y = f2bf(s[i][1]);
            pk.z = f2bf(s[i][2]); pk.w = f2bf(s[i][3]);
            *(ushort4*)&pw[l16 * 72 + i * 16 + quad * 4] = pk;
        }

#pragma unroll
        for (int kk = 0; kk < 2; ++kk) {
            bf16x8 pf = *(const bf16x8*)&pw[l16 * 72 + kk * 32 + quad * 8];
            bf16x8 vf[4];
#pragma unroll
            for (int jd = 0; jd < 4; ++jd)
                vf[jd] = *(const bf16x8*)&lV[(jd * 16 + l16) * 72 + kk * 32 + quad * 8];
#pragma unroll
            for (int jd = 0; jd < 4; ++jd)
                oacc[jd] = __builtin_amdgcn_mfma_f32_16x16x32_bf16(pf, vf[jd], oacc[jd], 0, 0, 0);
        }
    }

    float ir[4];
#pragma unroll
    for (int r = 0; r < 4; ++r)
        ir[r] = 1.f / __shfl(lrun, quad * 4 + r, 64);
#pragma unroll
    for (int r = 0; r < 4; ++r) {
        int qg = q0 + wave * 16 + quad * 4 + r;
        unsigned short* orow = op + (rowbase + qg) * (size_t)1024 + hoff;
#pragma unroll
        for (int jd = 0; jd < 4; ++jd)
            orow[jd * 16 + l16] = f2bf(oacc[jd][r] * ir[r]);
    }
}

// ---------------------------------------------------------------- launch
extern "C" void kernel_launch(void* const* d_in, const int* in_sizes, int n_in,
                              void* d_out, int out_size, void* d_ws, size_t ws_size,
                              hipStream_t stream)
{
    const float* x     = (const float*)d_in[0];
    const float* ctx   = (const float*)d_in[1];
    const float* ln1_g = (const float*)d_in[2];
    const float* ln1_b = (const float*)d_in[3];
    const float* qkv_w = (const float*)d_in[4];
    const float* qkv_b = (const float*)d_in[5];
    const float* aow   = (const float*)d_in[6];
    const float* aob   = (const float*)d_in[7];
    const float* lnc_g = (const float*)d_in[8];
    const float* lnc_b = (const float*)d_in[9];
    const float* q_w   = (const float*)d_in[10];
    const float* q_b   = (const float*)d_in[11];
    const float* kv_w  = (const float*)d_in[12];
    const float* kv_b  = (const float*)d_in[13];
    const float* cow   = (const float*)d_in[14];
    const float* cob   = (const float*)d_in[15];
    const float* ln2_g = (const float*)d_in[16];
    const float* ln2_b = (const float*)d_in[17];
    const float* f1w   = (const float*)d_in[18];
    const float* f1b   = (const float*)d_in[19];
    const float* f2w   = (const float*)d_in[20];
    const float* f2b   = (const float*)d_in[21];

    char* ws = (char*)d_ws;
    size_t off = 0;
    auto alloc = [&](size_t bytes) {
        char* p = ws + off;
        off += (bytes + 255) & ~(size_t)255;
        return p;
    };

    unsigned short* WtQKV = (unsigned short*)alloc((size_t)3072 * 1024 * 2);
    unsigned short* WtAO  = (unsigned short*)alloc((size_t)1024 * 1024 * 2);
    unsigned short* WtQ   = (unsigned short*)alloc((size_t)1024 * 1024 * 2);
    unsigned short* WtKV  = (unsigned short*)alloc((size_t)2048 * 1024 * 2);
    unsigned short* WtCO  = (unsigned short*)alloc((size_t)1024 * 1024 * 2);
    unsigned short* WtF1  = (unsigned short*)alloc((size_t)4096 * 1024 * 2);
    unsigned short* WtF2  = (unsigned short*)alloc((size_t)1024 * 4096 * 2);
    unsigned short* hA    = (unsigned short*)alloc((size_t)BT * 1024 * 2);
    unsigned short* ctxb  = (unsigned short*)alloc((size_t)BT * 1024 * 2);
    unsigned short* qkvb  = (unsigned short*)alloc((size_t)BT * 3072 * 2);
    unsigned short* o1    = (unsigned short*)alloc((size_t)BT * 1024 * 2);
    float*          x1    = (float*)alloc((size_t)BT * 1024 * 4);
    unsigned short* qb    = (unsigned short*)alloc((size_t)BT * 1024 * 2);
    unsigned short* kvb   = (unsigned short*)alloc((size_t)BT * 2048 * 2);
    unsigned short* o2    = (unsigned short*)alloc((size_t)BT * 1024 * 2);
    float*          x2    = (float*)alloc((size_t)BT * 1024 * 4);
    unsigned short* mid   = (unsigned short*)alloc((size_t)BT * 4096 * 2);
    unsigned short* vT1   = (unsigned short*)alloc((size_t)BT * 1024 * 2);
    unsigned short* vT2   = (unsigned short*)alloc((size_t)BT * 1024 * 2);

    float* partials = (float*)qkvb;   // dead by FFN2 time; 33.5 MB fits easily

    TransJobs J;
    J.W[0]=qkv_w; J.Wt[0]=WtQKV; J.K[0]=1024; J.N[0]=3072;
    J.W[1]=aow;   J.Wt[1]=WtAO;  J.K[1]=1024; J.N[1]=1024;
    J.W[2]=q_w;   J.Wt[2]=WtQ;   J.K[2]=1024; J.N[2]=1024;
    J.W[3]=kv_w;  J.Wt[3]=WtKV;  J.K[3]=1024; J.N[3]=2048;
    J.W[4]=cow;   J.Wt[4]=WtCO;  J.K[4]=1024; J.N[4]=1024;
    J.W[5]=f1w;   J.Wt[5]=WtF1;  J.K[5]=1024; J.N[5]=4096;
    J.W[6]=f2w;   J.Wt[6]=WtF2;  J.K[6]=4096; J.N[6]=1024;
    int acc = 0;
    for (int j = 0; j < 7; ++j) {
        J.start[j] = acc;
        acc += (J.N[j] / 32) * (J.K[j] / 32);
    }
    J.start[7] = acc;

    dim3 tb(32, 8);

    // prep: all weight transposes + LN(x) + cast(ctx) in one launch
    prep_kernel<<<acc + 2 * BT, 256, 0, stream>>>(J, x, ln1_g, ln1_b, hA, ctx, ctxb);

    // self-attention block
    gemm_bt<0><<<dim3(3072/128, BT/128), 256, 0, stream>>>(hA, WtQKV, qkv_b, nullptr, qkvb, BT, 3072, 1024);
    transpose_v<<<dim3(2, TT/32, 64), tb, 0, stream>>>(qkvb + 2048, vT1, 3072);
    attn_kernel<<<dim3(TT/64, 64), 256, 0, stream>>>(qkvb, qkvb + 1024, vT1, o1, 3072, 3072, 1);
    gemm_small2<<<dim3(1024/128, BT/64), 256, 0, stream>>>(o1, WtAO, aob, x, x1, BT, 1024, 1024);

    // cross-attention block
    ln_kernel<<<BT, 256, 0, stream>>>(x1, lnc_g, lnc_b, hA);
    gemm_dual<<<dim3(1024/128 + 2048/128, BT/128), 256, 0, stream>>>(
        hA, WtQ, q_b, qb, 1024, 1024/128,
        ctxb, WtKV, kv_b, kvb, 2048, 1024);
    transpose_v<<<dim3(2, TT/32, 64), tb, 0, stream>>>(kvb + 1024, vT2, 2048);
    attn_kernel<<<dim3(TT/64, 64), 256, 0, stream>>>(qb, kvb, vT2, o2, 1024, 2048, 0);
    gemm_small2<<<dim3(1024/128, BT/64), 256, 0, stream>>>(o2, WtCO, cob, x1, x2, BT, 1024, 1024);

    // FFN block
    ln_kernel<<<BT, 256, 0, stream>>>(x2, ln2_g, ln2_b, hA);
    gemm_bt<1><<<dim3(4096/128, BT/128), 256, 0, stream>>>(hA, WtF1, f1b, nullptr, mid, BT, 4096, 1024);
    gemm_splitk<<<dim3(1024/128, BT/128, 2), 256, 0, stream>>>(mid, WtF2, partials, BT, 1024, 4096, 2048);
    reduce2<<<BT * 1024 / 4 / 256, 256, 0, stream>>>(partials, f2b, x2, (float*)d_out, BT * 1024);
}